// Round 5
// baseline (283.514 us; speedup 1.0000x reference)
//
#include <hip/hip_runtime.h>
#include <hip/hip_bf16.h>

typedef __bf16 bf16x8 __attribute__((ext_vector_type(8)));
typedef float  f32x4  __attribute__((ext_vector_type(4)));

#define MFMA16 __builtin_amdgcn_mfma_f32_16x16x32_bf16

__device__ __forceinline__ float fast_tanh(float x) {
    float e = __builtin_amdgcn_exp2f(x * 2.8853900817779268f);
    return 1.0f - 2.0f * __builtin_amdgcn_rcpf(e + 1.0f);
}

// kappa permutation: stored k-index s -> physical k-dim
//   kphys = (s & ~31) | ((s&1)<<4) | ((s>>1)&15)
__device__ __forceinline__ int kinv(int ke) {
    return (ke & ~31) | ((ke & 1) << 4) | ((ke >> 1) & 15);
}

__device__ __forceinline__ bf16x8 cvt2(const float4 a, const float4 b) {
    bf16x8 t;
    t[0] = (__bf16)a.x; t[1] = (__bf16)a.y; t[2] = (__bf16)a.z; t[3] = (__bf16)a.w;
    t[4] = (__bf16)b.x; t[5] = (__bf16)b.y; t[6] = (__bf16)b.z; t[7] = (__bf16)b.w;
    return t;
}

// ---- weight pre-conversion: f32 -> bf16 MFMA B-fragments in d_ws ----
// table1 ws[0,131072):      [w:8][kk:8][nbl:2][lane:64][j:8 bf16]   (GEMM1)
// table2 ws[131072,196608): [q4:4][kk:8][nbl:2][lane:64][j:8]       (GEMM2, kappa rows)
// table3 ws[196608,212992): [q4:4][kk:4][lane:64][j:8]              (GEMM3, kappa rows)
__global__ __launch_bounds__(256) void preconv_kernel(
    const float* __restrict__ WFOH, const float* __restrict__ WFOM,
    const float* __restrict__ rhid2Layer, const float* __restrict__ routLayer,
    char* __restrict__ ws)
{
    const int f = blockIdx.x * 256 + threadIdx.x;
    bf16x8 v;
    char* dst;
    if (f < 8192) {
        const int lane = f & 63, t = f >> 6;
        const int nbl = t & 1, kk = (t >> 1) & 7, w = t >> 4;
        const int g = lane >> 4, c = lane & 15;
        const int nb = 32 * w + 16 * nbl;
        const float* Wsrc = (nb < 128) ? WFOH : WFOM;
        const int col = (nb + c) & 127;
        #pragma unroll
        for (int j = 0; j < 8; ++j) v[j] = (__bf16)Wsrc[(32 * kk + 8 * g + j) * 128 + col];
        dst = ws + (size_t)f * 16;
    } else if (f < 12288) {
        const int f2 = f - 8192;
        const int lane = f2 & 63, t = f2 >> 6;
        const int nbl = t & 1, kk = (t >> 1) & 7, q4 = t >> 4;
        const int g = lane >> 4, c = lane & 15;
        const int n2 = 32 * q4 + 16 * nbl + c;
        #pragma unroll
        for (int j = 0; j < 8; ++j) v[j] = (__bf16)rhid2Layer[kinv(32 * kk + 8 * g + j) * 128 + n2];
        dst = ws + 131072 + (size_t)f2 * 16;
    } else if (f < 13312) {
        const int f3 = f - 12288;
        const int lane = f3 & 63, t = f3 >> 6;
        const int kk = t & 3, q4 = t >> 2;
        const int g = lane >> 4, c = lane & 15;
        const int n3 = 16 * q4 + c;
        #pragma unroll
        for (int j = 0; j < 8; ++j) v[j] = (__bf16)routLayer[kinv(32 * kk + 8 * g + j) * 64 + n3];
        dst = ws + 196608 + (size_t)f3 * 16;
    } else {
        return;
    }
    *(bf16x8*)dst = v;
}

template<bool PRE>
__device__ __forceinline__ bf16x8 wfrag1(const char* ws, const float* WFOH, const float* WFOM,
                                         int w, int kk, int nbl, int lane) {
    if constexpr (PRE) {
        return *(const bf16x8*)(ws + (size_t)w * 16384 + kk * 2048 + nbl * 1024 + lane * 16);
    } else {
        const int g = lane >> 4, c = lane & 15;
        const int nb = 32 * w + 16 * nbl;
        const float* Wsrc = (nb < 128) ? WFOH : WFOM;
        const int col = (nb + c) & 127;
        bf16x8 v;
        #pragma unroll
        for (int j = 0; j < 8; ++j) v[j] = (__bf16)Wsrc[(32 * kk + 8 * g + j) * 128 + col];
        return v;
    }
}
template<bool PRE>
__device__ __forceinline__ bf16x8 wfrag2(const char* ws, const float* rhid2Layer,
                                         int q4, int kk, int nbl, int lane) {
    if constexpr (PRE) {
        return *(const bf16x8*)(ws + 131072 + (size_t)q4 * 16384 + kk * 2048 + nbl * 1024 + lane * 16);
    } else {
        const int g = lane >> 4, c = lane & 15;
        const int n2 = 32 * q4 + 16 * nbl + c;
        bf16x8 v;
        #pragma unroll
        for (int j = 0; j < 8; ++j) v[j] = (__bf16)rhid2Layer[kinv(32 * kk + 8 * g + j) * 128 + n2];
        return v;
    }
}
template<bool PRE>
__device__ __forceinline__ bf16x8 wfrag3(const char* ws, const float* routLayer,
                                         int q4, int kk, int lane) {
    if constexpr (PRE) {
        return *(const bf16x8*)(ws + 196608 + (size_t)q4 * 4096 + kk * 1024 + lane * 16);
    } else {
        const int g = lane >> 4, c = lane & 15;
        const int n3 = 16 * q4 + c;
        bf16x8 v;
        #pragma unroll
        for (int j = 0; j < 8; ++j) v[j] = (__bf16)routLayer[kinv(32 * kk + 8 * g + j) * 64 + n3];
        return v;
    }
}

// M_TILE = 64 rows/tile, 512 threads (8 waves), 64KB LDS -> 2 blocks/CU.
template<bool PRE>
__global__ __launch_bounds__(512, 4) void rel_kernel(
    const float* __restrict__ fwd, const float* __restrict__ bwd,
    const int* __restrict__ gold_heads, const int* __restrict__ gold_rels,
    const float* __restrict__ WFOH, const float* __restrict__ WFOM,
    const float* __restrict__ rcatBias, const float* __restrict__ rhid2Layer,
    const float* __restrict__ rhid2Bias, const float* __restrict__ routLayer,
    const float* __restrict__ routBias, const char* __restrict__ ws,
    float* __restrict__ out, int E, int NT)
{
    // LDS (aliased; 2D tiles XOR-swizzled with ((row&7)<<4) on bytes):
    //  [0,32K):  cat 64x256 bf16 | h2 64x128 bf16 in [0,16K) | fixup f32 in [16K,21K)
    //  [32K,64K): h 64x256 bf16 (kappa) | sc 64x64 f32 in [32K,48K)
    __shared__ __align__(16) char smem[65536];
    __shared__ int sh_nfix;
    __shared__ int sh_fixlist[16];

    char* const sh_cat = smem;
    char* const sh_h   = smem + 32768;
    char* const sh_h2  = smem;            // alias: cat dead after GEMM1 k-loop
    char* const sh_sc  = smem + 32768;    // alias: h dead after GEMM2 k-loop
    float* const fx_cat = (float*)(smem + 16384);   // 256
    float* const fx_h   = fx_cat + 256;             // 256
    float* const fx_h2  = fx_h + 256;               // 128
    float* const fx_p   = fx_h2 + 128;              // 512

    const int tid   = threadIdx.x;
    const int w     = tid >> 6;
    const int lane  = tid & 63;
    const int row16 = lane & 15;
    const int g     = lane >> 4;
    const int xm    = (row16 & 7) << 4;
    const int mw    = w >> 2;       // GEMM3 row-half
    const int nw    = w & 3;        // GEMM3 label-block

    const int r_s = tid >> 3;       // staging row (64 rows)
    const int q_s = tid & 7;        // staging eighth (32 floats each)
    const int xr  = (r_s & 7) << 4;

    const float rcb0 = rcatBias[32 * w + row16];
    const float rcb1 = rcatBias[32 * w + 16 + row16];
    const float r2b  = rhid2Bias[16 * w + row16];
    const float rob  = routBias[16 * nw + row16];

    // ---- prologue gather for the first tile ----
    bf16x8 pfb[4];
    {
        const int e = blockIdx.x * 64 + r_s;
        int nh = 0;
        if (q_s < 4 && e < E) nh = gold_heads[e];
        if (e < E) {
            const float* src = (q_s < 4) ? (fwd + (size_t)nh * 128 + 32 * q_s)
                                         : (bwd + (size_t)(e + 1) * 128 + 32 * (q_s - 4));
            const float4* p4 = (const float4*)src;
            #pragma unroll
            for (int i = 0; i < 4; ++i) pfb[i] = cvt2(p4[2 * i], p4[2 * i + 1]);
        } else {
            #pragma unroll
            for (int i = 0; i < 4; ++i) pfb[i] = cvt2(make_float4(0.f,0.f,0.f,0.f), make_float4(0.f,0.f,0.f,0.f));
        }
    }

    for (int tile = blockIdx.x; tile < NT; tile += gridDim.x) {
        const int e0 = tile * 64;
        const int tnext = tile + gridDim.x;
        const bool hn = tnext < NT;

        // ---- stage cat tile (bf16, swizzled) from pfb ----
        #pragma unroll
        for (int i = 0; i < 4; ++i)
            *(bf16x8*)(sh_cat + r_s * 512 + ((64 * q_s + 16 * i) ^ xr)) = pfb[i];

        // next tile's head index (latency hidden under GEMM1)
        int nh = 0;
        bool gv = false;
        if (hn) {
            const int en = tnext * 64 + r_s;
            gv = en < E;
            if (q_s < 4 && gv) nh = gold_heads[en];
        }
        __syncthreads();                                   // B1: cat ready

        // ---- GEMM1: h(64x256) = cat @ [WFOH|WFOM], tanh(+rcatBias) ----
        f32x4 acc1[4][2];
        #pragma unroll
        for (int i = 0; i < 4; ++i) {
            acc1[i][0] = (f32x4){0.f, 0.f, 0.f, 0.f};
            acc1[i][1] = (f32x4){0.f, 0.f, 0.f, 0.f};
        }
        {
            bf16x8 b0 = wfrag1<PRE>(ws, WFOH, WFOM, w, 0, 0, lane);
            bf16x8 b1 = wfrag1<PRE>(ws, WFOH, WFOM, w, 0, 1, lane);
            #pragma unroll 1   // rolled; next-kk frags prefetched over MFMA cluster
            for (int kk = 0; kk < 8; ++kk) {
                const bf16x8 nb0 = wfrag1<PRE>(ws, WFOH, WFOM, w, (kk + 1) & 7, 0, lane);
                const bf16x8 nb1 = wfrag1<PRE>(ws, WFOH, WFOM, w, (kk + 1) & 7, 1, lane);
                const int ko = (64 * kk + 16 * g) ^ xm;
                #pragma unroll
                for (int mb = 0; mb < 4; ++mb) {
                    const bf16x8 a = *(const bf16x8*)(sh_cat + (16 * mb + row16) * 512 + ko);
                    acc1[mb][0] = MFMA16(a, b0, acc1[mb][0], 0, 0, 0);
                    acc1[mb][1] = MFMA16(a, b1, acc1[mb][1], 0, 0, 0);
                }
                b0 = nb0; b1 = nb1;
            }
        }
        #pragma unroll
        for (int mb = 0; mb < 4; ++mb) {
            #pragma unroll
            for (int r = 0; r < 4; ++r) {
                const int row = 16 * mb + 4 * g + r;
                // kappa-packed pair (cols 32w+row16, 32w+16+row16)
                __bf16 p0 = (__bf16)fast_tanh(acc1[mb][0][r] + rcb0);
                __bf16 p1 = (__bf16)fast_tanh(acc1[mb][1][r] + rcb1);
                unsigned short u0 = __builtin_bit_cast(unsigned short, p0);
                unsigned short u1 = __builtin_bit_cast(unsigned short, p1);
                *(unsigned*)(sh_h + row * 512 + ((64 * w + 4 * row16) ^ ((row & 7) << 4)))
                    = (unsigned)u0 | ((unsigned)u1 << 16);
            }
        }
        __syncthreads();                                   // B2: h ready

        // ---- T14: issue next tile's gather batch A ----
        const float* gsrc = nullptr;
        if (hn) {
            const int en = tnext * 64 + r_s;
            gsrc = (q_s < 4) ? (fwd + (size_t)nh * 128 + 32 * q_s)
                             : (bwd + (size_t)(en + 1) * 128 + 32 * (q_s - 4));
        }
        float4 pfA[4];
        if (hn && gv) {
            const float4* p4 = (const float4*)gsrc;
            #pragma unroll
            for (int i = 0; i < 4; ++i) pfA[i] = p4[i];
        } else {
            #pragma unroll
            for (int i = 0; i < 4; ++i) pfA[i] = make_float4(0.f, 0.f, 0.f, 0.f);
        }

        // ---- GEMM2: h2(64x128) = h @ W2(kappa), tanh(+rhid2Bias) ----
        // wave w owns h2-cols [16w,16w+16)
        f32x4 acc2[4];
        #pragma unroll
        for (int i = 0; i < 4; ++i) acc2[i] = (f32x4){0.f, 0.f, 0.f, 0.f};
        {
            bf16x8 b2 = wfrag2<PRE>(ws, rhid2Layer, w >> 1, 0, w & 1, lane);
            #pragma unroll 1
            for (int kk = 0; kk < 8; ++kk) {
                const bf16x8 nb2 = wfrag2<PRE>(ws, rhid2Layer, w >> 1, (kk + 1) & 7, w & 1, lane);
                const int ko = (64 * kk + 16 * g) ^ xm;
                #pragma unroll
                for (int mb = 0; mb < 4; ++mb) {
                    const bf16x8 a = *(const bf16x8*)(sh_h + (16 * mb + row16) * 512 + ko);
                    acc2[mb] = MFMA16(a, b2, acc2[mb], 0, 0, 0);
                }
                b2 = nb2;
            }
        }
        // convert batch A -> pfb[0..1]; issue batch B
        pfb[0] = cvt2(pfA[0], pfA[1]);
        pfb[1] = cvt2(pfA[2], pfA[3]);
        float4 pfB[4];
        if (hn && gv) {
            const float4* p4 = (const float4*)gsrc;
            #pragma unroll
            for (int i = 0; i < 4; ++i) pfB[i] = p4[4 + i];
        } else {
            #pragma unroll
            for (int i = 0; i < 4; ++i) pfB[i] = make_float4(0.f, 0.f, 0.f, 0.f);
        }
        // h2 epilogue: single u16 per (mb,r), kappa2 position s = 32*(w>>1)+2*row16+(w&1)
        #pragma unroll
        for (int mb = 0; mb < 4; ++mb) {
            #pragma unroll
            for (int r = 0; r < 4; ++r) {
                const int row = 16 * mb + 4 * g + r;
                __bf16 p = (__bf16)fast_tanh(acc2[mb][r] + r2b);
                *(unsigned short*)(sh_h2 + row * 256 +
                    ((64 * (w >> 1) + 4 * row16 + 2 * (w & 1)) ^ ((row & 7) << 4)))
                    = __builtin_bit_cast(unsigned short, p);
            }
        }
        __syncthreads();                                   // B3: h2 ready

        // ---- GEMM3: sc(64x64) = h2 @ W3(kappa2) + routBias ----
        // wave (mw,nw): rows [32mw,32mw+32), labels [16nw,16nw+16)
        if (tid == 0) sh_nfix = 0;
        f32x4 acc3[2];
        acc3[0] = (f32x4){0.f, 0.f, 0.f, 0.f};
        acc3[1] = (f32x4){0.f, 0.f, 0.f, 0.f};
        #pragma unroll
        for (int kk = 0; kk < 4; ++kk) {
            const bf16x8 b = wfrag3<PRE>(ws, routLayer, nw, kk, lane);
            const int ko = (64 * kk + 16 * g) ^ xm;
            #pragma unroll
            for (int i = 0; i < 2; ++i) {
                const bf16x8 a = *(const bf16x8*)(sh_h2 + (32 * mw + 16 * i + row16) * 256 + ko);
                acc3[i] = MFMA16(a, b, acc3[i], 0, 0, 0);
            }
        }
        // convert batch B -> pfb[2..3]
        pfb[2] = cvt2(pfB[0], pfB[1]);
        pfb[3] = cvt2(pfB[2], pfB[3]);
        #pragma unroll
        for (int i = 0; i < 2; ++i) {
            #pragma unroll
            for (int r = 0; r < 4; ++r) {
                const int row = 32 * mw + 16 * i + 4 * g + r;
                const int col = 16 * nw + row16;
                *(float*)(sh_sc + row * 256 + ((4 * col) ^ ((row & 7) << 4))) = acc3[i][r] + rob;
            }
        }
        __syncthreads();                                   // B4: sc ready

        // ---- hinge: 8 threads per edge row ----
        {
            const int r = tid >> 3, q = tid & 7;
            const int e = e0 + r;
            const int gold = (e < E) ? gold_rels[e] : 0;
            const int xrh = (r & 7) << 4;
            const f32x4 s0 = *(const f32x4*)(sh_sc + r * 256 + ((32 * q) ^ xrh));
            const f32x4 s1 = *(const f32x4*)(sh_sc + r * 256 + ((32 * q + 16) ^ xrh));
            float gs = -3.0e38f, ws_ = -3.0e38f;
            #pragma unroll
            for (int cc = 0; cc < 4; ++cc) {
                const int lab0 = 8 * q + cc, lab1 = 8 * q + 4 + cc;
                if (lab0 == gold) gs = s0[cc]; else ws_ = fmaxf(ws_, s0[cc]);
                if (lab1 == gold) gs = s1[cc]; else ws_ = fmaxf(ws_, s1[cc]);
            }
            gs = fmaxf(gs, __shfl_xor(gs, 1)); ws_ = fmaxf(ws_, __shfl_xor(ws_, 1));
            gs = fmaxf(gs, __shfl_xor(gs, 2)); ws_ = fmaxf(ws_, __shfl_xor(ws_, 2));
            gs = fmaxf(gs, __shfl_xor(gs, 4)); ws_ = fmaxf(ws_, __shfl_xor(ws_, 4));
            if (q == 0 && e < E) {
                out[e] = (gs < ws_ + 1.0f) ? (ws_ - gs) : 0.0f;
                // hinge discontinuous at margin==1 -> exact f32 fixup
                if (fabsf((gs - ws_) - 1.0f) < 0.125f) {
                    const int idx = atomicAdd(&sh_nfix, 1);
                    if (idx < 16) sh_fixlist[idx] = r;
                }
            }
        }
        __syncthreads();                                   // B5: fixlist ready

        // ---- exact f32 recompute of margin-boundary edges (rare) ----
        int nf = sh_nfix; if (nf > 16) nf = 16;
        for (int fi = 0; fi < nf; ++fi) {
            const int e = e0 + sh_fixlist[fi];
            if (tid < 256) {
                const int head = gold_heads[e];
                fx_cat[tid] = (tid < 128) ? fwd[(size_t)head * 128 + tid]
                                          : bwd[(size_t)(e + 1) * 128 + (tid - 128)];
            }
            __syncthreads();
            {   // layer1: 2 k-halves x 256 dims (coalesced weight reads)
                const int d = tid & 255, half = tid >> 8;
                const float* base = (d < 128) ? WFOH : WFOM;
                const int col = d & 127;
                float s = 0.f;
                #pragma unroll 8
                for (int k = 128 * half; k < 128 * half + 128; ++k) s += fx_cat[k] * base[k * 128 + col];
                fx_p[half * 256 + d] = s;
            }
            __syncthreads();
            if (tid < 256) fx_h[tid] = tanhf(fx_p[tid] + fx_p[256 + tid] + rcatBias[tid]);
            __syncthreads();
            {   // layer2: 4 k-quarters x 128 dims
                const int d2 = tid & 127, qq = tid >> 7;
                float s = 0.f;
                #pragma unroll 8
                for (int k = 64 * qq; k < 64 * qq + 64; ++k) s += fx_h[k] * rhid2Layer[k * 128 + d2];
                fx_p[qq * 128 + d2] = s;
            }
            __syncthreads();
            if (tid < 128) fx_h2[tid] = tanhf(fx_p[tid] + fx_p[128 + tid] + fx_p[256 + tid] + fx_p[384 + tid] + rhid2Bias[tid]);
            __syncthreads();
            if (tid < 64) {   // layer3 + hinge in one wave
                float s = 0.f;
                #pragma unroll 8
                for (int k = 0; k < 128; ++k) s += fx_h2[k] * routLayer[k * 64 + tid];
                const float v = s + routBias[tid];
                const int gold = gold_rels[e];
                float gs = (tid == gold) ? v : -3.0e38f;
                float wv = (tid == gold) ? -3.0e38f : v;
                #pragma unroll
                for (int o = 1; o < 64; o <<= 1) {
                    gs = fmaxf(gs, __shfl_xor(gs, o));
                    wv = fmaxf(wv, __shfl_xor(wv, o));
                }
                if (tid == 0) out[e] = (gs < wv + 1.0f) ? (wv - gs) : 0.0f;
            }
            __syncthreads();
        }
    }
}

extern "C" void kernel_launch(void* const* d_in, const int* in_sizes, int n_in,
                              void* d_out, int out_size, void* d_ws, size_t ws_size,
                              hipStream_t stream) {
    const float* fwd        = (const float*)d_in[0];
    const float* bwd        = (const float*)d_in[1];
    const int*   gold_heads = (const int*)d_in[2];
    const int*   gold_rels  = (const int*)d_in[3];
    const float* WFOH       = (const float*)d_in[4];
    const float* WFOM       = (const float*)d_in[5];
    const float* rcatBias   = (const float*)d_in[7];   // d_in[6] rhidBias unused by reference
    const float* rhid2      = (const float*)d_in[8];
    const float* rhid2Bias  = (const float*)d_in[9];
    const float* rout       = (const float*)d_in[10];
    const float* routBias   = (const float*)d_in[11];
    float* out = (float*)d_out;

    const int E = in_sizes[2];
    if (E <= 0) return;
    const int NT = (E + 63) / 64;
    const int grid = NT < 512 ? NT : 512;

    if (ws_size >= (size_t)212992) {
        hipLaunchKernelGGL(preconv_kernel, dim3(52), dim3(256), 0, stream,
                           WFOH, WFOM, rhid2, rout, (char*)d_ws);
        hipLaunchKernelGGL((rel_kernel<true>), dim3(grid), dim3(512), 0, stream,
                           fwd, bwd, gold_heads, gold_rels, WFOH, WFOM, rcatBias,
                           rhid2, rhid2Bias, rout, routBias, (const char*)d_ws, out, E, NT);
    } else {
        hipLaunchKernelGGL((rel_kernel<false>), dim3(grid), dim3(512), 0, stream,
                           fwd, bwd, gold_heads, gold_rels, WFOH, WFOM, rcatBias,
                           rhid2, rhid2Bias, rout, routBias, (const char*)nullptr, out, E, NT);
    }
}

// Round 6
// 186.453 us; speedup vs baseline: 1.5206x; 1.5206x over previous
//
#include <hip/hip_runtime.h>
#include <hip/hip_bf16.h>

typedef __bf16 bf16x8 __attribute__((ext_vector_type(8)));
typedef float  f32x4  __attribute__((ext_vector_type(4)));

#define MFMA16 __builtin_amdgcn_mfma_f32_16x16x32_bf16

__device__ __forceinline__ float fast_tanh(float x) {
    float e = __builtin_amdgcn_exp2f(x * 2.8853900817779268f);
    return 1.0f - 2.0f * __builtin_amdgcn_rcpf(e + 1.0f);
}

// kappa permutation: stored k-index s -> physical k-dim
//   kphys = (s & ~31) | ((s&1)<<4) | ((s>>1)&15)
__device__ __forceinline__ int kinv(int ke) {
    return (ke & ~31) | ((ke & 1) << 4) | ((ke >> 1) & 15);
}

__device__ __forceinline__ bf16x8 cvt2(const float4 a, const float4 b) {
    bf16x8 t;
    t[0] = (__bf16)a.x; t[1] = (__bf16)a.y; t[2] = (__bf16)a.z; t[3] = (__bf16)a.w;
    t[4] = (__bf16)b.x; t[5] = (__bf16)b.y; t[6] = (__bf16)b.z; t[7] = (__bf16)b.w;
    return t;
}

// ---- weight pre-conversion: f32 -> bf16 MFMA B-fragments in d_ws ----
// table1 ws[0,131072):      [w:8][kk:8][nbl:2][lane:64][j:8 bf16]   (GEMM1)
// table2 ws[131072,196608): [q4:4][kk:8][nbl:2][lane:64][j:8]       (GEMM2, kappa rows)
// table3 ws[196608,212992): [q4:4][kk:4][lane:64][j:8]              (GEMM3, kappa rows)
__global__ __launch_bounds__(256) void preconv_kernel(
    const float* __restrict__ WFOH, const float* __restrict__ WFOM,
    const float* __restrict__ rhid2Layer, const float* __restrict__ routLayer,
    char* __restrict__ ws)
{
    const int f = blockIdx.x * 256 + threadIdx.x;
    bf16x8 v;
    char* dst;
    if (f < 8192) {
        const int lane = f & 63, t = f >> 6;
        const int nbl = t & 1, kk = (t >> 1) & 7, w = t >> 4;
        const int g = lane >> 4, c = lane & 15;
        const int nb = 32 * w + 16 * nbl;
        const float* Wsrc = (nb < 128) ? WFOH : WFOM;
        const int col = (nb + c) & 127;
        #pragma unroll
        for (int j = 0; j < 8; ++j) v[j] = (__bf16)Wsrc[(32 * kk + 8 * g + j) * 128 + col];
        dst = ws + (size_t)f * 16;
    } else if (f < 12288) {
        const int f2 = f - 8192;
        const int lane = f2 & 63, t = f2 >> 6;
        const int nbl = t & 1, kk = (t >> 1) & 7, q4 = t >> 4;
        const int g = lane >> 4, c = lane & 15;
        const int n2 = 32 * q4 + 16 * nbl + c;
        #pragma unroll
        for (int j = 0; j < 8; ++j) v[j] = (__bf16)rhid2Layer[kinv(32 * kk + 8 * g + j) * 128 + n2];
        dst = ws + 131072 + (size_t)f2 * 16;
    } else if (f < 13312) {
        const int f3 = f - 12288;
        const int lane = f3 & 63, t = f3 >> 6;
        const int kk = t & 3, q4 = t >> 2;
        const int g = lane >> 4, c = lane & 15;
        const int n3 = 16 * q4 + c;
        #pragma unroll
        for (int j = 0; j < 8; ++j) v[j] = (__bf16)routLayer[kinv(32 * kk + 8 * g + j) * 64 + n3];
        dst = ws + 196608 + (size_t)f3 * 16;
    } else {
        return;
    }
    *(bf16x8*)dst = v;
}

template<bool PRE>
__device__ __forceinline__ bf16x8 wfrag1(const char* ws, const float* WFOH, const float* WFOM,
                                         int w, int kk, int nbl, int lane) {
    if constexpr (PRE) {
        return *(const bf16x8*)(ws + (size_t)w * 16384 + kk * 2048 + nbl * 1024 + lane * 16);
    } else {
        const int g = lane >> 4, c = lane & 15;
        const int nb = 32 * w + 16 * nbl;
        const float* Wsrc = (nb < 128) ? WFOH : WFOM;
        const int col = (nb + c) & 127;
        bf16x8 v;
        #pragma unroll
        for (int j = 0; j < 8; ++j) v[j] = (__bf16)Wsrc[(32 * kk + 8 * g + j) * 128 + col];
        return v;
    }
}
template<bool PRE>
__device__ __forceinline__ bf16x8 wfrag2(const char* ws, const float* rhid2Layer,
                                         int q4, int kk, int nbl, int lane) {
    if constexpr (PRE) {
        return *(const bf16x8*)(ws + 131072 + (size_t)q4 * 16384 + kk * 2048 + nbl * 1024 + lane * 16);
    } else {
        const int g = lane >> 4, c = lane & 15;
        const int n2 = 32 * q4 + 16 * nbl + c;
        bf16x8 v;
        #pragma unroll
        for (int j = 0; j < 8; ++j) v[j] = (__bf16)rhid2Layer[kinv(32 * kk + 8 * g + j) * 128 + n2];
        return v;
    }
}
template<bool PRE>
__device__ __forceinline__ bf16x8 wfrag3(const char* ws, const float* routLayer,
                                         int q4, int kk, int lane) {
    if constexpr (PRE) {
        return *(const bf16x8*)(ws + 196608 + (size_t)q4 * 4096 + kk * 1024 + lane * 16);
    } else {
        const int g = lane >> 4, c = lane & 15;
        const int n3 = 16 * q4 + c;
        bf16x8 v;
        #pragma unroll
        for (int j = 0; j < 8; ++j) v[j] = (__bf16)routLayer[kinv(32 * kk + 8 * g + j) * 64 + n3];
        return v;
    }
}

// M_TILE=64, 512 threads (8 waves), 64KB LDS, launch_bounds(512,2): 2 blocks/CU,
// VGPR cap 128 (empirical: 2nd arg == min blocks/CU on this toolchain).
template<bool PRE>
__global__ __launch_bounds__(512, 2) void rel_kernel(
    const float* __restrict__ fwd, const float* __restrict__ bwd,
    const int* __restrict__ gold_heads, const int* __restrict__ gold_rels,
    const float* __restrict__ WFOH, const float* __restrict__ WFOM,
    const float* __restrict__ rcatBias, const float* __restrict__ rhid2Layer,
    const float* __restrict__ rhid2Bias, const float* __restrict__ routLayer,
    const float* __restrict__ routBias, const char* __restrict__ ws,
    int* __restrict__ fixcnt, int* __restrict__ fixlist, int fixcap,
    float* __restrict__ out, int E, int NT)
{
    // LDS (aliased; 2D tiles XOR-swizzled with ((row&7)<<4) on bytes):
    //  [0,32K):  cat 64x256 bf16 | h2 64x128 bf16 in [0,16K)
    //  [32K,64K): h 64x256 bf16 (kappa) | sc 64x64 f32 in [32K,48K)
    __shared__ __align__(16) char smem[65536];

    char* const sh_cat = smem;
    char* const sh_h   = smem + 32768;
    char* const sh_h2  = smem;            // alias: cat dead after GEMM1 k-loop
    char* const sh_sc  = smem + 32768;    // alias: h dead after GEMM2 k-loop

    const int tid   = threadIdx.x;
    const int w     = tid >> 6;
    const int lane  = tid & 63;
    const int row16 = lane & 15;
    const int g     = lane >> 4;
    const int xm    = (row16 & 7) << 4;
    const int mw    = w >> 2;       // GEMM3 row-half
    const int nw    = w & 3;        // GEMM3 label-block

    const int r_s = tid >> 3;       // staging row (64 rows)
    const int q_s = tid & 7;        // staging eighth (32 floats each)
    const int xr  = (r_s & 7) << 4;

    const float rcb0 = rcatBias[32 * w + row16];
    const float rcb1 = rcatBias[32 * w + 16 + row16];
    const float r2b  = rhid2Bias[16 * w + row16];
    const float rob  = routBias[16 * nw + row16];

    // ---- prologue gather for the first tile ----
    bf16x8 pfb[4];
    {
        const int e = blockIdx.x * 64 + r_s;
        int nh = 0;
        if (q_s < 4 && e < E) nh = gold_heads[e];
        if (e < E) {
            const float* src = (q_s < 4) ? (fwd + (size_t)nh * 128 + 32 * q_s)
                                         : (bwd + (size_t)(e + 1) * 128 + 32 * (q_s - 4));
            const float4* p4 = (const float4*)src;
            #pragma unroll
            for (int i = 0; i < 4; ++i) pfb[i] = cvt2(p4[2 * i], p4[2 * i + 1]);
        } else {
            #pragma unroll
            for (int i = 0; i < 4; ++i) pfb[i] = cvt2(make_float4(0.f,0.f,0.f,0.f), make_float4(0.f,0.f,0.f,0.f));
        }
    }

    for (int tile = blockIdx.x; tile < NT; tile += gridDim.x) {
        const int e0 = tile * 64;
        const int tnext = tile + gridDim.x;
        const bool hn = tnext < NT;

        // ---- stage cat tile (bf16, swizzled) from pfb ----
        #pragma unroll
        for (int i = 0; i < 4; ++i)
            *(bf16x8*)(sh_cat + r_s * 512 + ((64 * q_s + 16 * i) ^ xr)) = pfb[i];

        // next tile's head index (latency hidden under GEMM1)
        int nh = 0;
        bool gv = false;
        if (hn) {
            const int en = tnext * 64 + r_s;
            gv = en < E;
            if (q_s < 4 && gv) nh = gold_heads[en];
        }
        __syncthreads();                                   // B1: cat ready

        // ---- GEMM1: h(64x256) = cat @ [WFOH|WFOM], tanh(+rcatBias) ----
        f32x4 acc1[4][2];
        #pragma unroll
        for (int i = 0; i < 4; ++i) {
            acc1[i][0] = (f32x4){0.f, 0.f, 0.f, 0.f};
            acc1[i][1] = (f32x4){0.f, 0.f, 0.f, 0.f};
        }
        {
            bf16x8 b0 = wfrag1<PRE>(ws, WFOH, WFOM, w, 0, 0, lane);
            bf16x8 b1 = wfrag1<PRE>(ws, WFOH, WFOM, w, 0, 1, lane);
            #pragma unroll 1   // rolled; next-kk frags prefetched over MFMA cluster
            for (int kk = 0; kk < 8; ++kk) {
                const bf16x8 nb0 = wfrag1<PRE>(ws, WFOH, WFOM, w, (kk + 1) & 7, 0, lane);
                const bf16x8 nb1 = wfrag1<PRE>(ws, WFOH, WFOM, w, (kk + 1) & 7, 1, lane);
                const int ko = (64 * kk + 16 * g) ^ xm;
                #pragma unroll
                for (int mb = 0; mb < 4; ++mb) {
                    const bf16x8 a = *(const bf16x8*)(sh_cat + (16 * mb + row16) * 512 + ko);
                    acc1[mb][0] = MFMA16(a, b0, acc1[mb][0], 0, 0, 0);
                    acc1[mb][1] = MFMA16(a, b1, acc1[mb][1], 0, 0, 0);
                }
                b0 = nb0; b1 = nb1;
            }
        }
        #pragma unroll
        for (int mb = 0; mb < 4; ++mb) {
            #pragma unroll
            for (int r = 0; r < 4; ++r) {
                const int row = 16 * mb + 4 * g + r;
                // kappa-packed pair (cols 32w+row16, 32w+16+row16)
                __bf16 p0 = (__bf16)fast_tanh(acc1[mb][0][r] + rcb0);
                __bf16 p1 = (__bf16)fast_tanh(acc1[mb][1][r] + rcb1);
                unsigned short u0 = __builtin_bit_cast(unsigned short, p0);
                unsigned short u1 = __builtin_bit_cast(unsigned short, p1);
                *(unsigned*)(sh_h + row * 512 + ((64 * w + 4 * row16) ^ ((row & 7) << 4)))
                    = (unsigned)u0 | ((unsigned)u1 << 16);
            }
        }
        __syncthreads();                                   // B2: h ready

        // ---- T14: issue next tile's gather batch A ----
        const float* gsrc = nullptr;
        if (hn) {
            const int en = tnext * 64 + r_s;
            gsrc = (q_s < 4) ? (fwd + (size_t)nh * 128 + 32 * q_s)
                             : (bwd + (size_t)(en + 1) * 128 + 32 * (q_s - 4));
        }
        float4 pfA[4];
        if (hn && gv) {
            const float4* p4 = (const float4*)gsrc;
            #pragma unroll
            for (int i = 0; i < 4; ++i) pfA[i] = p4[i];
        } else {
            #pragma unroll
            for (int i = 0; i < 4; ++i) pfA[i] = make_float4(0.f, 0.f, 0.f, 0.f);
        }

        // ---- GEMM2: h2(64x128) = h @ W2(kappa), tanh(+rhid2Bias) ----
        // wave w owns h2-cols [16w,16w+16)
        f32x4 acc2[4];
        #pragma unroll
        for (int i = 0; i < 4; ++i) acc2[i] = (f32x4){0.f, 0.f, 0.f, 0.f};
        {
            bf16x8 b2 = wfrag2<PRE>(ws, rhid2Layer, w >> 1, 0, w & 1, lane);
            #pragma unroll 1
            for (int kk = 0; kk < 8; ++kk) {
                const bf16x8 nb2 = wfrag2<PRE>(ws, rhid2Layer, w >> 1, (kk + 1) & 7, w & 1, lane);
                const int ko = (64 * kk + 16 * g) ^ xm;
                #pragma unroll
                for (int mb = 0; mb < 4; ++mb) {
                    const bf16x8 a = *(const bf16x8*)(sh_h + (16 * mb + row16) * 512 + ko);
                    acc2[mb] = MFMA16(a, b2, acc2[mb], 0, 0, 0);
                }
                b2 = nb2;
            }
        }
        // convert batch A -> pfb[0..1]; issue batch B
        pfb[0] = cvt2(pfA[0], pfA[1]);
        pfb[1] = cvt2(pfA[2], pfA[3]);
        float4 pfB[4];
        if (hn && gv) {
            const float4* p4 = (const float4*)gsrc;
            #pragma unroll
            for (int i = 0; i < 4; ++i) pfB[i] = p4[4 + i];
        } else {
            #pragma unroll
            for (int i = 0; i < 4; ++i) pfB[i] = make_float4(0.f, 0.f, 0.f, 0.f);
        }
        // h2 epilogue: single u16 per (mb,r), kappa2 position s = 32*(w>>1)+2*row16+(w&1)
        #pragma unroll
        for (int mb = 0; mb < 4; ++mb) {
            #pragma unroll
            for (int r = 0; r < 4; ++r) {
                const int row = 16 * mb + 4 * g + r;
                __bf16 p = (__bf16)fast_tanh(acc2[mb][r] + r2b);
                *(unsigned short*)(sh_h2 + row * 256 +
                    ((64 * (w >> 1) + 4 * row16 + 2 * (w & 1)) ^ ((row & 7) << 4)))
                    = __builtin_bit_cast(unsigned short, p);
            }
        }
        __syncthreads();                                   // B3: h2 ready

        // ---- GEMM3: sc(64x64) = h2 @ W3(kappa2) + routBias ----
        // wave (mw,nw): rows [32mw,32mw+32), labels [16nw,16nw+16)
        f32x4 acc3[2];
        acc3[0] = (f32x4){0.f, 0.f, 0.f, 0.f};
        acc3[1] = (f32x4){0.f, 0.f, 0.f, 0.f};
        #pragma unroll
        for (int kk = 0; kk < 4; ++kk) {
            const bf16x8 b = wfrag3<PRE>(ws, routLayer, nw, kk, lane);
            const int ko = (64 * kk + 16 * g) ^ xm;
            #pragma unroll
            for (int i = 0; i < 2; ++i) {
                const bf16x8 a = *(const bf16x8*)(sh_h2 + (32 * mw + 16 * i + row16) * 256 + ko);
                acc3[i] = MFMA16(a, b, acc3[i], 0, 0, 0);
            }
        }
        // convert batch B -> pfb[2..3]
        pfb[2] = cvt2(pfB[0], pfB[1]);
        pfb[3] = cvt2(pfB[2], pfB[3]);
        #pragma unroll
        for (int i = 0; i < 2; ++i) {
            #pragma unroll
            for (int r = 0; r < 4; ++r) {
                const int row = 32 * mw + 16 * i + 4 * g + r;
                const int col = 16 * nw + row16;
                *(float*)(sh_sc + row * 256 + ((4 * col) ^ ((row & 7) << 4))) = acc3[i][r] + rob;
            }
        }
        __syncthreads();                                   // B4: sc ready

        // ---- hinge: 8 threads per edge row; boundary edges -> global fixlist ----
        {
            const int r = tid >> 3, q = tid & 7;
            const int e = e0 + r;
            const int gold = (e < E) ? gold_rels[e] : 0;
            const int xrh = (r & 7) << 4;
            const f32x4 s0 = *(const f32x4*)(sh_sc + r * 256 + ((32 * q) ^ xrh));
            const f32x4 s1 = *(const f32x4*)(sh_sc + r * 256 + ((32 * q + 16) ^ xrh));
            float gs = -3.0e38f, ws_ = -3.0e38f;
            #pragma unroll
            for (int cc = 0; cc < 4; ++cc) {
                const int lab0 = 8 * q + cc, lab1 = 8 * q + 4 + cc;
                if (lab0 == gold) gs = s0[cc]; else ws_ = fmaxf(ws_, s0[cc]);
                if (lab1 == gold) gs = s1[cc]; else ws_ = fmaxf(ws_, s1[cc]);
            }
            gs = fmaxf(gs, __shfl_xor(gs, 1)); ws_ = fmaxf(ws_, __shfl_xor(ws_, 1));
            gs = fmaxf(gs, __shfl_xor(gs, 2)); ws_ = fmaxf(ws_, __shfl_xor(ws_, 2));
            gs = fmaxf(gs, __shfl_xor(gs, 4)); ws_ = fmaxf(ws_, __shfl_xor(ws_, 4));
            if (q == 0 && e < E) {
                out[e] = (gs < ws_ + 1.0f) ? (ws_ - gs) : 0.0f;
                // hinge is discontinuous at margin==1: exact f32 recompute later
                if (fabsf((gs - ws_) - 1.0f) < 0.125f && fixcap > 0) {
                    const int idx = atomicAdd(fixcnt, 1);
                    if (idx < fixcap) fixlist[idx] = e;
                }
            }
        }
        // no barrier: B1 of the next iteration orders hinge reads vs sh_h writes
    }
}

// ---- exact f32 recompute of margin-boundary edges (~1e-3 of edges) ----
__global__ __launch_bounds__(256) void fixup_kernel(
    const float* __restrict__ fwd, const float* __restrict__ bwd,
    const int* __restrict__ gold_heads, const int* __restrict__ gold_rels,
    const float* __restrict__ WFOH, const float* __restrict__ WFOM,
    const float* __restrict__ rcatBias, const float* __restrict__ rhid2Layer,
    const float* __restrict__ rhid2Bias, const float* __restrict__ routLayer,
    const float* __restrict__ routBias,
    const int* __restrict__ fixcnt, const int* __restrict__ fixlist, int fixcap,
    float* __restrict__ out)
{
    __shared__ float fx_cat[256];
    __shared__ float fx_h[256];
    __shared__ float fx_h2[128];
    __shared__ float fx_p[256];
    int n = *fixcnt;
    if (n > fixcap) n = fixcap;
    const int tid = threadIdx.x;
    for (int i = blockIdx.x; i < n; i += gridDim.x) {
        const int e = fixlist[i];
        {
            const int head = gold_heads[e];
            fx_cat[tid] = (tid < 128) ? fwd[(size_t)head * 128 + tid]
                                      : bwd[(size_t)(e + 1) * 128 + (tid - 128)];
        }
        __syncthreads();
        {   // layer1: one h-dim per thread, coalesced weight reads
            const float* base = (tid < 128) ? WFOH : WFOM;
            const int col = tid & 127;
            float s = 0.f;
            #pragma unroll 8
            for (int k = 0; k < 256; ++k) s += fx_cat[k] * base[k * 128 + col];
            fx_h[tid] = tanhf(s + rcatBias[tid]);
        }
        __syncthreads();
        {   // layer2: 2 k-halves x 128 dims
            const int d = tid & 127, hh = tid >> 7;
            float s = 0.f;
            #pragma unroll 8
            for (int k = 128 * hh; k < 128 * hh + 128; ++k) s += fx_h[k] * rhid2Layer[k * 128 + d];
            fx_p[hh * 128 + d] = s;
        }
        __syncthreads();
        if (tid < 128) fx_h2[tid] = tanhf(fx_p[tid] + fx_p[128 + tid] + rhid2Bias[tid]);
        __syncthreads();
        {   // layer3: 4 k-quarters x 64 labels
            const int d = tid & 63, qq = tid >> 6;
            float s = 0.f;
            #pragma unroll 8
            for (int k = 32 * qq; k < 32 * qq + 32; ++k) s += fx_h2[k] * routLayer[k * 64 + d];
            fx_p[qq * 64 + d] = s;
        }
        __syncthreads();
        if (tid < 64) {
            const float v = fx_p[tid] + fx_p[64 + tid] + fx_p[128 + tid] + fx_p[192 + tid] + routBias[tid];
            const int gold = gold_rels[e];
            float gs = (tid == gold) ? v : -3.0e38f;
            float wv = (tid == gold) ? -3.0e38f : v;
            #pragma unroll
            for (int o = 1; o < 64; o <<= 1) {
                gs = fmaxf(gs, __shfl_xor(gs, o));
                wv = fmaxf(wv, __shfl_xor(wv, o));
            }
            if (tid == 0) out[e] = (gs < wv + 1.0f) ? (wv - gs) : 0.0f;
        }
        __syncthreads();
    }
}

extern "C" void kernel_launch(void* const* d_in, const int* in_sizes, int n_in,
                              void* d_out, int out_size, void* d_ws, size_t ws_size,
                              hipStream_t stream) {
    const float* fwd        = (const float*)d_in[0];
    const float* bwd        = (const float*)d_in[1];
    const int*   gold_heads = (const int*)d_in[2];
    const int*   gold_rels  = (const int*)d_in[3];
    const float* WFOH       = (const float*)d_in[4];
    const float* WFOM       = (const float*)d_in[5];
    const float* rcatBias   = (const float*)d_in[7];   // d_in[6] rhidBias unused by reference
    const float* rhid2      = (const float*)d_in[8];
    const float* rhid2Bias  = (const float*)d_in[9];
    const float* rout       = (const float*)d_in[10];
    const float* routBias   = (const float*)d_in[11];
    float* out = (float*)d_out;

    const int E = in_sizes[2];
    if (E <= 0) return;
    const int NT = (E + 63) / 64;
    const int grid = NT < 512 ? NT : 512;

    const size_t TAB = 212992;                 // bf16 weight tables
    const int FIXCAP = 8192;
    const size_t FIX_BYTES = 4 + 4 * (size_t)FIXCAP;

    bool pre = ws_size >= TAB + FIX_BYTES;
    int* fixcnt = nullptr;
    int* fixlist = nullptr;
    int fixcap = 0;
    if (pre) {
        fixcnt = (int*)((char*)d_ws + TAB);
        fixlist = fixcnt + 1;
        fixcap = FIXCAP;
    } else if (ws_size >= FIX_BYTES) {
        fixcnt = (int*)d_ws;
        fixlist = fixcnt + 1;
        fixcap = FIXCAP;
    }
    if (fixcap) hipMemsetAsync(fixcnt, 0, 4, stream);

    if (pre) {
        hipLaunchKernelGGL(preconv_kernel, dim3(52), dim3(256), 0, stream,
                           WFOH, WFOM, rhid2, rout, (char*)d_ws);
        hipLaunchKernelGGL((rel_kernel<true>), dim3(grid), dim3(512), 0, stream,
                           fwd, bwd, gold_heads, gold_rels, WFOH, WFOM, rcatBias,
                           rhid2, rhid2Bias, rout, routBias, (const char*)d_ws,
                           fixcnt, fixlist, fixcap, out, E, NT);
    } else {
        hipLaunchKernelGGL((rel_kernel<false>), dim3(grid), dim3(512), 0, stream,
                           fwd, bwd, gold_heads, gold_rels, WFOH, WFOM, rcatBias,
                           rhid2, rhid2Bias, rout, routBias, (const char*)nullptr,
                           fixcnt, fixlist, fixcap, out, E, NT);
    }
    if (fixcap) {
        hipLaunchKernelGGL(fixup_kernel, dim3(120), dim3(256), 0, stream,
                           fwd, bwd, gold_heads, gold_rels, WFOH, WFOM, rcatBias,
                           rhid2, rhid2Bias, rout, routBias,
                           fixcnt, fixlist, fixcap, out);
    }
}